// Round 4
// baseline (645.908 us; speedup 1.0000x reference)
//
#include <hip/hip_runtime.h>
#include <hip/hip_bf16.h>

#define N_NODE 50000
#define N_USED 50000
#define N_EDGE 800000
#define N_REL  8
#define NB     16          // nodes per block
#define NTHREADS 1024
#define NWAVES 16
#define PADF   136         // f32 words per agg row: even ch at [0..63], odd at [68..131]
#define PADB   68          // uint stride of repacked bf16 row

typedef __bf16 bf16x8 __attribute__((ext_vector_type(8)));
typedef float  f32x4  __attribute__((ext_vector_type(4)));

__device__ __forceinline__ float bf_lo(unsigned u) {
    union { unsigned i; float f; } v; v.i = u << 16; return v.f;
}
__device__ __forceinline__ float bf_hi(unsigned u) {
    union { unsigned i; float f; } v; v.i = u & 0xffff0000u; return v.f;
}
__device__ __forceinline__ unsigned pack2(float a, float b) {
    __hip_bfloat16 ha = __float2bfloat16(a), hb = __float2bfloat16(b);
    unsigned short ua = *reinterpret_cast<unsigned short*>(&ha);
    unsigned short ub = *reinterpret_cast<unsigned short*>(&hb);
    return (unsigned)ua | ((unsigned)ub << 16);
}

// ---- x (fp32, [N_USED][128]) -> xb (bf16) ----
__global__ __launch_bounds__(256) void k_cvt_x(const float* __restrict__ x,
                                               __hip_bfloat16* __restrict__ xb) {
    int i = blockIdx.x * 256 + threadIdx.x;
    float4 v = reinterpret_cast<const float4*>(x)[i];
    __hip_bfloat16 h0 = __float2bfloat16(v.x);
    __hip_bfloat16 h1 = __float2bfloat16(v.y);
    __hip_bfloat16 h2 = __float2bfloat16(v.z);
    __hip_bfloat16 h3 = __float2bfloat16(v.w);
    ushort4 o;
    o.x = *reinterpret_cast<unsigned short*>(&h0);
    o.y = *reinterpret_cast<unsigned short*>(&h1);
    o.z = *reinterpret_cast<unsigned short*>(&h2);
    o.w = *reinterpret_cast<unsigned short*>(&h3);
    reinterpret_cast<ushort4*>(xb)[i] = o;
}

// ---- W [r][c][h] fp32 -> Wt [r][h][c] bf16 ----
__global__ __launch_bounds__(256) void k_cvt_w(const float* __restrict__ w,
                                               __hip_bfloat16* __restrict__ wt) {
    int i = blockIdx.x * 256 + threadIdx.x;       // 131072 elems
    int r = i >> 14, c = (i >> 7) & 127, h = i & 127;
    wt[(((size_t)r << 7) + h) * 128 + c] = __float2bfloat16(w[i]);
}

// ---- fused: edge-parallel LDS aggregation + K-split MFMA ----
__global__ __launch_bounds__(NTHREADS, 8)
void k_fused(const __hip_bfloat16* __restrict__ xb,
             const __hip_bfloat16* __restrict__ wt,
             const int* __restrict__ ptr,
             const int* __restrict__ idx,
             const int* __restrict__ rel,
             float* __restrict__ out)
{
    __shared__ float aggf[N_REL * NB * PADF];     // 69632 B -> 2 blocks/CU
    __shared__ int ptr_s[NB + 1];

    const int tid  = threadIdx.x;
    const int lane = tid & 63;
    const int w    = tid >> 6;
    const int t0   = blockIdx.x * NB;             // 3125 * 16 = 50000 exact

    // zero agg
    const f32x4 z4 = {0.f, 0.f, 0.f, 0.f};
    for (int i = tid * 4; i < N_REL * NB * PADF; i += NTHREADS * 4)
        *reinterpret_cast<f32x4*>(&aggf[i]) = z4;
    if (tid <= NB) ptr_s[tid] = ptr[t0 + tid];
    __syncthreads();

    // ---- phase 1: 16 waves split the edge range; LDS-atomic accumulate ----
    {
        const int e_lo = ptr_s[0];
        const int e_hi = ptr_s[NB];
        const int bnd  = (lane < NB) ? ptr_s[lane + 1] : 0x7fffffff;
        const int nedge = e_hi - e_lo;
        const int chunk = (nedge + NWAVES - 1) / NWAVES;
        const int e0 = e_lo + w * chunk;
        const int e1 = min(e0 + chunk, e_hi);
        const unsigned* xu = (const unsigned*)xb;   // lane owns ch {2l, 2l+1}

        for (int e = e0; e < e1; e += 8) {
            const int m = e1 - e;
            int ob[8], ib[8];
#pragma unroll
            for (int b = 0; b < 8; ++b) {
                int ee = (b < m) ? e + b : e0;
                ib[b] = idx[ee];
                ob[b] = rel[ee];
            }
#pragma unroll
            for (int b = 0; b < 8; ++b) {
                int node = (int)__popcll(__ballot(bnd <= e + b));
                ob[b] = ((ob[b] << 4) + node) * PADF;     // row base (f32 words)
            }
            unsigned ub[8];
#pragma unroll
            for (int b = 0; b < 8; ++b)
                ub[b] = xu[(size_t)ib[b] * 64 + lane];
#pragma unroll
            for (int b = 0; b < 8; ++b) {
                if (b < m) {
                    float* p = &aggf[ob[b]];
                    unsafeAtomicAdd(p + lane,      bf_lo(ub[b]));   // even ch
                    unsafeAtomicAdd(p + 68 + lane, bf_hi(ub[b]));   // odd ch
                }
            }
        }
    }
    __syncthreads();

    // ---- phase 2a: repack fp32 halves -> packed bf16 rows (in place) ----
    {
        const int row = tid >> 3;                 // 0..127  (= rel*NB + node)
        const int p   = tid & 7;                  // 8 ch-pairs each
        const float* sA = &aggf[row * PADF + p * 8];        // even channels
        const float* sB = &aggf[row * PADF + 68 + p * 8];   // odd channels
        f32x4 a0 = *reinterpret_cast<const f32x4*>(sA);
        f32x4 a1 = *reinterpret_cast<const f32x4*>(sA + 4);
        f32x4 b0 = *reinterpret_cast<const f32x4*>(sB);
        f32x4 b1 = *reinterpret_cast<const f32x4*>(sB + 4);
        __syncthreads();
        unsigned* dst = reinterpret_cast<unsigned*>(aggf) + row * PADB + p * 8;
        uint4 o0, o1;
        o0.x = pack2(a0[0], b0[0]); o0.y = pack2(a0[1], b0[1]);
        o0.z = pack2(a0[2], b0[2]); o0.w = pack2(a0[3], b0[3]);
        o1.x = pack2(a1[0], b1[0]); o1.y = pack2(a1[1], b1[1]);
        o1.z = pack2(a1[2], b1[2]); o1.w = pack2(a1[3], b1[3]);
        *reinterpret_cast<uint4*>(dst)     = o0;
        *reinterpret_cast<uint4*>(dst + 4) = o1;
    }
    __syncthreads();

    // ---- phase 2b: out[16][128] = agg[16][K=1024] @ Wstack[1024][128] ----
    // wave w: h-slice (w&7)*16, K-half (w>>3) covering rels 4*(w>>3)..+3
    const unsigned* aggu = reinterpret_cast<const unsigned*>(aggf);
    float* scratch = aggf + 9216;                 // floats; above bf16 region (8704)
    const int rlo = lane & 15, khi = lane >> 4;
    const int hsl = (w & 7) << 4;
    const int rbase = (w >> 3) << 2;
    const int h = hsl + rlo;
    f32x4 acc = {0.f, 0.f, 0.f, 0.f};
#pragma unroll 8
    for (int kc = 0; kc < 16; ++kc) {
        const int r  = rbase + (kc >> 2);
        const int cu = (kc & 3) * 16 + (khi << 2);          // uint offset in row
        bf16x8 afrag = *reinterpret_cast<const bf16x8*>(&aggu[((r << 4) + rlo) * PADB + cu]);
        bf16x8 bfrag = *reinterpret_cast<const bf16x8*>(
            &wt[(size_t)(((r << 7) + h) << 7) + (kc & 3) * 32 + (khi << 3)]);
        acc = __builtin_amdgcn_mfma_f32_16x16x32_bf16(afrag, bfrag, acc, 0, 0, 0);
    }
    if (w >= 8) {
        *reinterpret_cast<f32x4*>(&scratch[(((w - 8) << 6) + lane) << 2]) = acc;
    }
    __syncthreads();
    if (w < 8) {
        f32x4 part = *reinterpret_cast<const f32x4*>(&scratch[((w << 6) + lane) << 2]);
        acc[0] += part[0]; acc[1] += part[1]; acc[2] += part[2]; acc[3] += part[3];
        // C/D: col = lane&15 (h), row = (lane>>4)*4 + j (node)
#pragma unroll
        for (int j = 0; j < 4; ++j) {
            int n = t0 + (khi << 2) + j;
            out[(size_t)n * 128 + h] = acc[j];
        }
    }
}

// ---- fallback (tiny workspace): direct fp32 compute, slow but correct ----
__global__ __launch_bounds__(256) void k_direct(const float* __restrict__ x,
                                                const float* __restrict__ w,
                                                const int* __restrict__ ptr,
                                                const int* __restrict__ idx,
                                                const int* __restrict__ rel,
                                                float* __restrict__ out) {
    const int lane = threadIdx.x & 63;
    const int s = blockIdx.x * 4 + (threadIdx.x >> 6);
    if (s >= N_NODE) return;
    const int e0 = ptr[s], e1 = ptr[s + 1];
    const int h = lane * 2;
    float ax = 0.f, ay = 0.f;
    for (int e = e0; e < e1; ++e) {
        const float* xr = x + (size_t)idx[e] * 128;
        const float* wr = w + (size_t)rel[e] * 16384 + h;
        for (int c = 0; c < 128; ++c) {
            float xv = xr[c];
            ax += xv * wr[(size_t)c * 128];
            ay += xv * wr[(size_t)c * 128 + 1];
        }
    }
    float2 o = {ax, ay};
    reinterpret_cast<float2*>(out + (size_t)s * 128)[lane] = o;
}

extern "C" void kernel_launch(void* const* d_in, const int* in_sizes, int n_in,
                              void* d_out, int out_size, void* d_ws, size_t ws_size,
                              hipStream_t stream) {
    const float* x   = (const float*)d_in[0];
    const float* w   = (const float*)d_in[1];
    const int*   ptr = (const int*)d_in[2];
    const int*   idx = (const int*)d_in[3];
    const int*   rel = (const int*)d_in[4];
    float*       out = (float*)d_out;

    const size_t off_xb = 0;                        // 12,800,000 B
    const size_t off_wt = 12800000;                 //    262,144 B
    const size_t need   = off_wt + (size_t)N_REL * 128 * 128 * 2;

    if (ws_size >= need) {
        __hip_bfloat16* xb = (__hip_bfloat16*)((char*)d_ws + off_xb);
        __hip_bfloat16* wt = (__hip_bfloat16*)((char*)d_ws + off_wt);
        k_cvt_x<<<6250, 256, 0, stream>>>(x, xb);
        k_cvt_w<<<512, 256, 0, stream>>>(w, wt);
        k_fused<<<N_NODE / NB, NTHREADS, 0, stream>>>(xb, wt, ptr, idx, rel, out);
    } else {
        k_direct<<<12500, 256, 0, stream>>>(x, w, ptr, idx, rel, out);
    }
}

// Round 5
// 195.647 us; speedup vs baseline: 3.3014x; 3.3014x over previous
//
#include <hip/hip_runtime.h>
#include <hip/hip_bf16.h>

#define N_NODE 50000
#define N_USED 50000
#define N_EDGE 800000
#define N_REL  8
#define NB     16          // nodes per block (= waves per block)
#define NTHREADS 1024
#define NWAVES 16
#define PADF   136         // f32 words per agg row: even ch at [0..63], odd at [68..131]
#define PADB   68          // uint stride of repacked bf16 row

typedef __bf16 bf16x8 __attribute__((ext_vector_type(8)));
typedef float  f32x4  __attribute__((ext_vector_type(4)));

__device__ __forceinline__ float bf_lo(unsigned u) {
    union { unsigned i; float f; } v; v.i = u << 16; return v.f;
}
__device__ __forceinline__ float bf_hi(unsigned u) {
    union { unsigned i; float f; } v; v.i = u & 0xffff0000u; return v.f;
}
__device__ __forceinline__ unsigned pack2(float a, float b) {
    __hip_bfloat16 ha = __float2bfloat16(a), hb = __float2bfloat16(b);
    unsigned short ua = *reinterpret_cast<unsigned short*>(&ha);
    unsigned short ub = *reinterpret_cast<unsigned short*>(&hb);
    return (unsigned)ua | ((unsigned)ub << 16);
}

// ---- x (fp32, [N_USED][128]) -> xb (bf16) ----
__global__ __launch_bounds__(256) void k_cvt_x(const float* __restrict__ x,
                                               __hip_bfloat16* __restrict__ xb) {
    int i = blockIdx.x * 256 + threadIdx.x;
    float4 v = reinterpret_cast<const float4*>(x)[i];
    __hip_bfloat16 h0 = __float2bfloat16(v.x);
    __hip_bfloat16 h1 = __float2bfloat16(v.y);
    __hip_bfloat16 h2 = __float2bfloat16(v.z);
    __hip_bfloat16 h3 = __float2bfloat16(v.w);
    ushort4 o;
    o.x = *reinterpret_cast<unsigned short*>(&h0);
    o.y = *reinterpret_cast<unsigned short*>(&h1);
    o.z = *reinterpret_cast<unsigned short*>(&h2);
    o.w = *reinterpret_cast<unsigned short*>(&h3);
    reinterpret_cast<ushort4*>(xb)[i] = o;
}

// ---- W [r][c][h] fp32 -> Wt [r][h][c] bf16 ----
__global__ __launch_bounds__(256) void k_cvt_w(const float* __restrict__ w,
                                               __hip_bfloat16* __restrict__ wt) {
    int i = blockIdx.x * 256 + threadIdx.x;       // 131072 elems
    int r = i >> 14, c = (i >> 7) & 127, h = i & 127;
    wt[(((size_t)r << 7) + h) * 128 + c] = __float2bfloat16(w[i]);
}

// ---- fused: wave-owned-node LDS RMW aggregation + K-split MFMA ----
__global__ __launch_bounds__(NTHREADS, 8)
void k_fused(const __hip_bfloat16* __restrict__ xb,
             const __hip_bfloat16* __restrict__ wt,
             const int* __restrict__ ptr,
             const int* __restrict__ idx,
             const int* __restrict__ rel,
             float* __restrict__ out)
{
    __shared__ float aggf[N_REL * NB * PADF];     // 69632 B -> 2 blocks/CU
    __shared__ int ptr_s[NB + 1];

    const int tid  = threadIdx.x;
    const int lane = tid & 63;
    const int w    = tid >> 6;                    // wave id = owned node
    const int t0   = blockIdx.x * NB;             // 3125 * 16 = 50000 exact

    // zero agg
    const f32x4 z4 = {0.f, 0.f, 0.f, 0.f};
    for (int i = tid * 4; i < N_REL * NB * PADF; i += NTHREADS * 4)
        *reinterpret_cast<f32x4*>(&aggf[i]) = z4;
    if (tid <= NB) ptr_s[tid] = ptr[t0 + tid];
    __syncthreads();

    // ---- phase 1: wave w exclusively aggregates node w (no atomics) ----
    {
        const int e0 = ptr_s[w];
        const int e1 = ptr_s[w + 1];
        const unsigned* xu = (const unsigned*)xb;   // lane owns ch {2l, 2l+1}

        for (int e = e0; e < e1; e += 8) {
            const int m = e1 - e;
            int ib[8], rb[8];
#pragma unroll
            for (int b = 0; b < 8; ++b) {
                int ee = (b < m) ? e + b : e0;      // uniform clamp
                ib[b] = idx[ee];
                rb[b] = rel[ee];
            }
            unsigned ub[8];
#pragma unroll
            for (int b = 0; b < 8; ++b)
                ub[b] = xu[(size_t)ib[b] * 64 + lane];
#pragma unroll
            for (int b = 0; b < 8; ++b) {
                if (b < m) {                        // uniform branch
                    const int row = (rb[b] * NB + w) * PADF;
                    float vlo = aggf[row + lane];
                    float vhi = aggf[row + 68 + lane];
                    aggf[row + lane]      = vlo + bf_lo(ub[b]);
                    aggf[row + 68 + lane] = vhi + bf_hi(ub[b]);
                }
            }
        }
    }
    __syncthreads();

    // ---- phase 2a: repack fp32 halves -> packed bf16 rows (in place) ----
    {
        const int row = tid >> 3;                 // 0..127  (= rel*NB + node)
        const int p   = tid & 7;                  // 8 ch-pairs each
        const float* sA = &aggf[row * PADF + p * 8];        // even channels
        const float* sB = &aggf[row * PADF + 68 + p * 8];   // odd channels
        f32x4 a0 = *reinterpret_cast<const f32x4*>(sA);
        f32x4 a1 = *reinterpret_cast<const f32x4*>(sA + 4);
        f32x4 b0 = *reinterpret_cast<const f32x4*>(sB);
        f32x4 b1 = *reinterpret_cast<const f32x4*>(sB + 4);
        __syncthreads();
        unsigned* dst = reinterpret_cast<unsigned*>(aggf) + row * PADB + p * 8;
        uint4 o0, o1;
        o0.x = pack2(a0[0], b0[0]); o0.y = pack2(a0[1], b0[1]);
        o0.z = pack2(a0[2], b0[2]); o0.w = pack2(a0[3], b0[3]);
        o1.x = pack2(a1[0], b1[0]); o1.y = pack2(a1[1], b1[1]);
        o1.z = pack2(a1[2], b1[2]); o1.w = pack2(a1[3], b1[3]);
        *reinterpret_cast<uint4*>(dst)     = o0;
        *reinterpret_cast<uint4*>(dst + 4) = o1;
    }
    __syncthreads();

    // ---- phase 2b: out[16][128] = agg[16][K=1024] @ Wstack[1024][128] ----
    // wave w: h-slice (w&7)*16, K-half (w>>3) covering rels 4*(w>>3)..+3
    const unsigned* aggu = reinterpret_cast<const unsigned*>(aggf);
    float* scratch = aggf + 9216;                 // floats; above bf16 region (8704)
    const int rlo = lane & 15, khi = lane >> 4;
    const int hsl = (w & 7) << 4;
    const int rbase = (w >> 3) << 2;
    const int h = hsl + rlo;
    f32x4 acc = {0.f, 0.f, 0.f, 0.f};
#pragma unroll 8
    for (int kc = 0; kc < 16; ++kc) {
        const int r  = rbase + (kc >> 2);
        const int cu = (kc & 3) * 16 + (khi << 2);          // uint offset in row
        bf16x8 afrag = *reinterpret_cast<const bf16x8*>(&aggu[((r << 4) + rlo) * PADB + cu]);
        bf16x8 bfrag = *reinterpret_cast<const bf16x8*>(
            &wt[(size_t)(((r << 7) + h) << 7) + (kc & 3) * 32 + (khi << 3)]);
        acc = __builtin_amdgcn_mfma_f32_16x16x32_bf16(afrag, bfrag, acc, 0, 0, 0);
    }
    if (w >= 8) {
        *reinterpret_cast<f32x4*>(&scratch[(((w - 8) << 6) + lane) << 2]) = acc;
    }
    __syncthreads();
    if (w < 8) {
        f32x4 part = *reinterpret_cast<const f32x4*>(&scratch[((w << 6) + lane) << 2]);
        acc[0] += part[0]; acc[1] += part[1]; acc[2] += part[2]; acc[3] += part[3];
        // C/D: col = lane&15 (h), row = (lane>>4)*4 + j (node)
#pragma unroll
        for (int j = 0; j < 4; ++j) {
            int n = t0 + (khi << 2) + j;
            out[(size_t)n * 128 + h] = acc[j];
        }
    }
}

// ---- fallback (tiny workspace): direct fp32 compute, slow but correct ----
__global__ __launch_bounds__(256) void k_direct(const float* __restrict__ x,
                                                const float* __restrict__ w,
                                                const int* __restrict__ ptr,
                                                const int* __restrict__ idx,
                                                const int* __restrict__ rel,
                                                float* __restrict__ out) {
    const int lane = threadIdx.x & 63;
    const int s = blockIdx.x * 4 + (threadIdx.x >> 6);
    if (s >= N_NODE) return;
    const int e0 = ptr[s], e1 = ptr[s + 1];
    const int h = lane * 2;
    float ax = 0.f, ay = 0.f;
    for (int e = e0; e < e1; ++e) {
        const float* xr = x + (size_t)idx[e] * 128;
        const float* wr = w + (size_t)rel[e] * 16384 + h;
        for (int c = 0; c < 128; ++c) {
            float xv = xr[c];
            ax += xv * wr[(size_t)c * 128];
            ay += xv * wr[(size_t)c * 128 + 1];
        }
    }
    float2 o = {ax, ay};
    reinterpret_cast<float2*>(out + (size_t)s * 128)[lane] = o;
}

extern "C" void kernel_launch(void* const* d_in, const int* in_sizes, int n_in,
                              void* d_out, int out_size, void* d_ws, size_t ws_size,
                              hipStream_t stream) {
    const float* x   = (const float*)d_in[0];
    const float* w   = (const float*)d_in[1];
    const int*   ptr = (const int*)d_in[2];
    const int*   idx = (const int*)d_in[3];
    const int*   rel = (const int*)d_in[4];
    float*       out = (float*)d_out;

    const size_t off_xb = 0;                        // 12,800,000 B
    const size_t off_wt = 12800000;                 //    262,144 B
    const size_t need   = off_wt + (size_t)N_REL * 128 * 128 * 2;

    if (ws_size >= need) {
        __hip_bfloat16* xb = (__hip_bfloat16*)((char*)d_ws + off_xb);
        __hip_bfloat16* wt = (__hip_bfloat16*)((char*)d_ws + off_wt);
        k_cvt_x<<<6250, 256, 0, stream>>>(x, xb);
        k_cvt_w<<<512, 256, 0, stream>>>(w, wt);
        k_fused<<<N_NODE / NB, NTHREADS, 0, stream>>>(xb, wt, ptr, idx, rel, out);
    } else {
        k_direct<<<12500, 256, 0, stream>>>(x, w, ptr, idx, rel, out);
    }
}

// Round 6
// 154.157 us; speedup vs baseline: 4.1899x; 1.2691x over previous
//
#include <hip/hip_runtime.h>
#include <hip/hip_bf16.h>

#define N_NODE 50000
#define N_USED 50000
#define N_EDGE 800000
#define N_REL  8

typedef __bf16 bf16x8 __attribute__((ext_vector_type(8)));
typedef float  f32x4  __attribute__((ext_vector_type(4)));

__device__ __forceinline__ float bf_lo(unsigned u) {
    union { unsigned i; float f; } v; v.i = u << 16; return v.f;
}
__device__ __forceinline__ float bf_hi(unsigned u) {
    union { unsigned i; float f; } v; v.i = u & 0xffff0000u; return v.f;
}
__device__ __forceinline__ unsigned pack2(float a, float b) {
    __hip_bfloat16 ha = __float2bfloat16(a), hb = __float2bfloat16(b);
    unsigned short ua = *reinterpret_cast<unsigned short*>(&ha);
    unsigned short ub = *reinterpret_cast<unsigned short*>(&hb);
    return (unsigned)ua | ((unsigned)ub << 16);
}

// ---- x (fp32, [N_USED][128]) -> xb (bf16) ----
__global__ __launch_bounds__(256) void k_cvt_x(const float* __restrict__ x,
                                               __hip_bfloat16* __restrict__ xb) {
    int i = blockIdx.x * 256 + threadIdx.x;
    float4 v = reinterpret_cast<const float4*>(x)[i];
    __hip_bfloat16 h0 = __float2bfloat16(v.x);
    __hip_bfloat16 h1 = __float2bfloat16(v.y);
    __hip_bfloat16 h2 = __float2bfloat16(v.z);
    __hip_bfloat16 h3 = __float2bfloat16(v.w);
    ushort4 o;
    o.x = *reinterpret_cast<unsigned short*>(&h0);
    o.y = *reinterpret_cast<unsigned short*>(&h1);
    o.z = *reinterpret_cast<unsigned short*>(&h2);
    o.w = *reinterpret_cast<unsigned short*>(&h3);
    reinterpret_cast<ushort4*>(xb)[i] = o;
}

// ---- W [r][c][h] fp32 -> Wt [r][h][c] bf16 ----
__global__ __launch_bounds__(256) void k_cvt_w(const float* __restrict__ w,
                                               __hip_bfloat16* __restrict__ wt) {
    int i = blockIdx.x * 256 + threadIdx.x;       // 131072 elems
    int r = i >> 14, c = (i >> 7) & 127, h = i & 127;
    wt[(((size_t)r << 7) + h) * 128 + c] = __float2bfloat16(w[i]);
}

// ---- stage A: aggregate-first segment sum on x ----
// 4 waves/block, wave = one node, NO barriers, wave-private LDS accumulator.
// agg[node][r][ch] bf16 out.
__global__ __launch_bounds__(256) void k_agg(const __hip_bfloat16* __restrict__ xb,
                                             const int* __restrict__ ptr,
                                             const int* __restrict__ idx,
                                             const int* __restrict__ rel,
                                             __hip_bfloat16* __restrict__ agg) {
    __shared__ float aggf[4 * N_REL * 128];       // 16 KB, wave-private 4KB regions

    const int lane = threadIdx.x & 63;
    const int w    = threadIdx.x >> 6;
    const int node = blockIdx.x * 4 + w;          // 12500*4 = 50000 exact
    float* mine = &aggf[w << 10];

    // zero own region (no sync needed — wave-private)
    const f32x4 z4 = {0.f, 0.f, 0.f, 0.f};
#pragma unroll
    for (int k = 0; k < 4; ++k)
        *reinterpret_cast<f32x4*>(&mine[(lane << 2) + (k << 8)]) = z4;

    const int e0 = ptr[node];
    const int e1 = ptr[node + 1];
    const unsigned* xu = (const unsigned*)xb;     // lane owns ch {2l, 2l+1}

    for (int e = e0; e < e1; e += 8) {
        const int m = e1 - e;
        int ib[8], rb[8];
#pragma unroll
        for (int b = 0; b < 8; ++b) {
            int ee = (b < m) ? e + b : e0;        // uniform clamp
            ib[b] = idx[ee];
            rb[b] = rel[ee];
        }
        unsigned ub[8];
#pragma unroll
        for (int b = 0; b < 8; ++b)
            ub[b] = xu[(size_t)ib[b] * 64 + lane];
#pragma unroll
        for (int b = 0; b < 8; ++b) {
            if (b < m) {                          // uniform branch
                float* p = mine + (rb[b] << 7);
                float vlo = p[lane], vhi = p[64 + lane];
                p[lane]      = vlo + bf_lo(ub[b]);
                p[64 + lane] = vhi + bf_hi(ub[b]);
            }
        }
    }

    // pack to bf16, write agg row (node): 8 rels x 256B coalesced
    unsigned* ao = reinterpret_cast<unsigned*>(agg) + (size_t)node * 512 + lane;
#pragma unroll
    for (int r = 0; r < N_REL; ++r) {
        const float* p = mine + (r << 7);
        ao[r << 6] = pack2(p[lane], p[64 + lane]);
    }
}

// ---- stage B: out[50000][128] = agg[50000][1024] @ Wstack[1024][128] ----
// 4 waves/block, 32 rows/wave (128/block), K = 8 rels * 128.
__global__ __launch_bounds__(256) void k_gemm2(const __hip_bfloat16* __restrict__ agg,
                                               const __hip_bfloat16* __restrict__ wt,
                                               float* __restrict__ out) {
    const int lane = threadIdx.x & 63;
    const int w    = threadIdx.x >> 6;
    const int n0   = blockIdx.x * 128 + w * 32;
    const int rlo  = lane & 15, khi = lane >> 4;

    f32x4 acc[2][8];
    const f32x4 zero = {0.f, 0.f, 0.f, 0.f};
#pragma unroll
    for (int rc = 0; rc < 2; ++rc)
#pragma unroll
        for (int nc = 0; nc < 8; ++nc) acc[rc][nc] = zero;

#pragma unroll
    for (int r = 0; r < N_REL; ++r) {
        bf16x8 a[2][4];
#pragma unroll
        for (int rc = 0; rc < 2; ++rc) {
            int row = n0 + rc * 16 + rlo;
            if (row >= N_NODE) row = N_NODE - 1;              // clamp; store guarded
            const __hip_bfloat16* ap = agg + (((size_t)row << 3) + r) * 128 + (khi << 3);
#pragma unroll
            for (int kc = 0; kc < 4; ++kc)
                a[rc][kc] = *reinterpret_cast<const bf16x8*>(ap + kc * 32);
        }
        const __hip_bfloat16* wr = wt + ((size_t)r << 14);     // [h][c]
#pragma unroll
        for (int nc = 0; nc < 8; ++nc) {
#pragma unroll
            for (int kc = 0; kc < 4; ++kc) {
                bf16x8 b = *reinterpret_cast<const bf16x8*>(
                    wr + ((size_t)(nc * 16 + rlo) << 7) + kc * 32 + (khi << 3));
                acc[0][nc] = __builtin_amdgcn_mfma_f32_16x16x32_bf16(a[0][kc], b, acc[0][nc], 0, 0, 0);
                acc[1][nc] = __builtin_amdgcn_mfma_f32_16x16x32_bf16(a[1][kc], b, acc[1][nc], 0, 0, 0);
            }
        }
    }
    // C/D: col = lane&15 (h within nc), row = (lane>>4)*4 + j (node within rc)
#pragma unroll
    for (int rc = 0; rc < 2; ++rc) {
#pragma unroll
        for (int j = 0; j < 4; ++j) {
            int n = n0 + rc * 16 + (khi << 2) + j;
            if (n < N_NODE) {
                float* dst = out + ((size_t)n << 7) + rlo;
#pragma unroll
                for (int nc = 0; nc < 8; ++nc)
                    dst[nc << 4] = acc[rc][nc][j];
            }
        }
    }
}

// ---- fallback (tiny workspace): direct fp32 compute, slow but correct ----
__global__ __launch_bounds__(256) void k_direct(const float* __restrict__ x,
                                                const float* __restrict__ w,
                                                const int* __restrict__ ptr,
                                                const int* __restrict__ idx,
                                                const int* __restrict__ rel,
                                                float* __restrict__ out) {
    const int lane = threadIdx.x & 63;
    const int s = blockIdx.x * 4 + (threadIdx.x >> 6);
    if (s >= N_NODE) return;
    const int e0 = ptr[s], e1 = ptr[s + 1];
    const int h = lane * 2;
    float ax = 0.f, ay = 0.f;
    for (int e = e0; e < e1; ++e) {
        const float* xr = x + (size_t)idx[e] * 128;
        const float* wr = w + (size_t)rel[e] * 16384 + h;
        for (int c = 0; c < 128; ++c) {
            float xv = xr[c];
            ax += xv * wr[(size_t)c * 128];
            ay += xv * wr[(size_t)c * 128 + 1];
        }
    }
    float2 o = {ax, ay};
    reinterpret_cast<float2*>(out + (size_t)s * 128)[lane] = o;
}

extern "C" void kernel_launch(void* const* d_in, const int* in_sizes, int n_in,
                              void* d_out, int out_size, void* d_ws, size_t ws_size,
                              hipStream_t stream) {
    const float* x   = (const float*)d_in[0];
    const float* w   = (const float*)d_in[1];
    const int*   ptr = (const int*)d_in[2];
    const int*   idx = (const int*)d_in[3];
    const int*   rel = (const int*)d_in[4];
    float*       out = (float*)d_out;

    const size_t off_xb  = 0;                       // 12,800,000 B
    const size_t off_wt  = 12800000;                //    262,144 B
    const size_t off_agg = 13062144;                // 102,400,000 B
    const size_t need    = off_agg + (size_t)N_NODE * N_REL * 128 * 2;

    if (ws_size >= need) {
        __hip_bfloat16* xb  = (__hip_bfloat16*)((char*)d_ws + off_xb);
        __hip_bfloat16* wt  = (__hip_bfloat16*)((char*)d_ws + off_wt);
        __hip_bfloat16* agg = (__hip_bfloat16*)((char*)d_ws + off_agg);
        k_cvt_x<<<6250, 256, 0, stream>>>(x, xb);
        k_cvt_w<<<512, 256, 0, stream>>>(w, wt);
        k_agg<<<N_NODE / 4, 256, 0, stream>>>(xb, ptr, idx, rel, agg);
        k_gemm2<<<(N_NODE + 127) / 128, 256, 0, stream>>>(agg, wt, out);
    } else {
        k_direct<<<12500, 256, 0, stream>>>(x, w, ptr, idx, rel, out);
    }
}